// Round 10
// baseline (447.352 us; speedup 1.0000x reference)
//
#include <hip/hip_runtime.h>

// ConvSA: B=8, C=256, H=W=48 (N=2304), E=512.
// out[b,e,i] = sum_j softmax_j(q[:,i].k[:,j]) * v[e,j] + v[e,i]
// R10: L2-residency round.
//  - attn v7 = R8's lean v4 + j-split x2 (jh): per-block KV 2.25 MB fits the
//    4 MB per-XCD L2 (was 4.5 MB -> L2/L3 thrash, the 182-us invariant).
//    Grid 1152 jh-major (b = bid&7 XCD pin); po/pm/pl partials + combine.
//  - conv3_all v2: 1-D grid 2304 with b in low 3 bits (XCD-pins X slab,
//    1.28 MB L2-resident; was unpinned -> 10 MB/XCD from L3) and W staged
//    through LDS (XOR-swizzled, shared by 4 waves -> W global traffic / 4).
//    Classic 2-barrier cc loop, X+W single-buffered (33 KB LDS, 3 blocks/CU).
//  - pack_feat/pack_w unchanged (R9-verified).

typedef _Float16 f16;
typedef _Float16 f16x4 __attribute__((ext_vector_type(4)));
typedef _Float16 f16x8 __attribute__((ext_vector_type(8)));
typedef float    f32x4  __attribute__((ext_vector_type(4)));
typedef float    f32x16 __attribute__((ext_vector_type(16)));

__device__ __forceinline__ f32x16 mfma16(f16x8 a, f16x8 b, f32x16 c) {
  return __builtin_amdgcn_mfma_f32_32x32x16_f16(a, b, c, 0, 0, 0);
}

__device__ __forceinline__ f16x8 f16x8_zero() {
  f16x8 z;
#pragma unroll
  for (int j = 0; j < 8; ++j) z[j] = (f16)0.f;
  return z;
}

#define NB   8
#define NC   256
#define NH   48
#define NN   2304     // 48*48
#define NE   512
#define HP   50       // padded H/W

// ---------------- pack kernels ----------------

// feat NCHW fp32 -> zero-padded NHWC [b][50][50][256] fp16 (R9-verified).
__global__ void pack_feat(const float* __restrict__ x, f16* __restrict__ p) {
  __shared__ f16 tx[48 * 258];
  const int b = blockIdx.x, yp = blockIdx.y;
  const int tid = threadIdx.x;
  f16* prow = p + ((size_t)(b * HP + yp) * HP) * NC;

  if (yp == 0 || yp == HP - 1) {
    for (int i = tid; i < 1600; i += 256)
      *(f16x8*)(prow + i * 8) = f16x8_zero();
    return;
  }
  const int y = yp - 1;
#pragma unroll 4
  for (int it = 0; it < 64; ++it) {
    int i = it * 256 + tid;
    int xsl = i & 63, c = i >> 6;
    if (xsl < 48) {
      float v = x[((b * NC + c) * NH + y) * NH + xsl];
      tx[xsl * 258 + c] = (f16)v;
    }
  }
  __syncthreads();
#pragma unroll
  for (int it = 0; it < 6; ++it) {
    int xq = (tid >> 5) + it * 8;
    int c0 = (tid & 31) * 8;
    f16x8 v = *(const f16x8*)(tx + xq * 258 + c0);
    *(f16x8*)(prow + (xq + 1) * NC + c0) = v;
  }
  if (tid < 64) {
    int xp = (tid >> 5) * (HP - 1);
    int c0 = (tid & 31) * 8;
    *(f16x8*)(prow + xp * NC + c0) = f16x8_zero();
  }
}

// W OIHW [512][256][3][3] fp32 -> A-frag blocks:
// [cc 16][t 9][et 16] x (el 32 x cl 16) contiguous 512-f16 (1 KB) blocks.
__global__ void pack_w(const float* __restrict__ wq, const float* __restrict__ wk,
                       const float* __restrict__ wv,
                       f16* __restrict__ oq, f16* __restrict__ ok,
                       f16* __restrict__ ov) {
  int idx = blockIdx.x * 256 + threadIdx.x;       // 9*512*256
  int c = idx & 255;
  int r = idx >> 8;
  int e = r & 511; int t = r >> 9;
  int src = (e * NC + c) * 9 + t;
  int cc = c >> 4, cl = c & 15, et = e >> 5, el = e & 31;
  int dst = ((cc * 9 + t) * 16 + et) * 512 + el * 16 + cl;
  oq[dst] = (f16)wq[src];
  ok[dst] = (f16)wk[src];
  ov[dst] = (f16)wv[src];
}

// ---------------- conv3x3 v2: b-pinned grid, W via LDS ----------------
// 1-D grid 2304: bid = b + 8*(strip + 6*(et + 16*F)). Block 256 thr,
// out tile 32 e x 384 pos (8 rows). X slab 10x50x16c (24 KB) + W slice
// 9 taps x 1 KB (9 KB, XOR-swizzled) both single-buffered; 2 barriers/cc.
__global__ __launch_bounds__(256, 3) void conv3_all(
    const f16* __restrict__ xh,
    const f16* __restrict__ wq, const f16* __restrict__ wk,
    const f16* __restrict__ wv,
    const float* __restrict__ bq, const float* __restrict__ bk,
    const float* __restrict__ bv,
    f16* __restrict__ oq, f16* __restrict__ okf, f16* __restrict__ ovf) {
  __shared__ __align__(16) f16 sx[12000];         // 24 KB
  __shared__ __align__(16) f16 sw[4608];          // 9 KB

  const int tid = threadIdx.x;
  const int lane = tid & 63, wvx = tid >> 6;
  const int l31 = lane & 31;
  const int koff = (lane >> 5) * 8;
  const int bid = blockIdx.x;
  const int b = bid & 7;
  int r = bid >> 3;                               // 0..287
  const int strip = r % 6; r /= 6;                // 0..47
  const int et = r & 15, F = r >> 4;
  const int e0 = et * 32;
  const int y0 = strip * 8;
  const f16* w = (F == 0) ? wq : (F == 1) ? wk : wv;
  const float* bias = (F == 0) ? bq : (F == 1) ? bk : bv;

  int pb[3];
#pragma unroll
  for (int nt = 0; nt < 3; ++nt) {
    int n = wvx * 96 + nt * 32 + l31;
    pb[nt] = (n / 48) * 50 + (n % 48);
  }

  // X staging coords: 4 chunks/thread
  int sgp[4], sgo[4]; bool sok[4]; int gbase[4];
#pragma unroll
  for (int u = 0; u < 4; ++u) {
    int g = u * 256 + tid;
    sok[u] = (g < 1000);
    int gg = sok[u] ? g : 999;
    sgp[u] = gg >> 1; sgo[u] = (gg & 1) * 8;
    int row = sgp[u] / 50, xx = sgp[u] % 50;
    gbase[u] = ((b * HP + y0 + row) * HP + xx) * NC + sgo[u];
  }
  // W staging coords: 3 chunks/thread (576 total), XOR-swizzled dest
  int wgt[3], wgj[3], wdst[3]; bool wok[3];
#pragma unroll
  for (int u = 0; u < 3; ++u) {
    int g = u * 256 + tid;
    wok[u] = (g < 576);
    int gg = wok[u] ? g : 575;
    wgt[u] = gg >> 6; wgj[u] = gg & 63;
    int wjs = wgj[u] ^ ((wgj[u] >> 3) & 7);
    wdst[u] = wgt[u] * 512 + wjs * 8;
  }
  // W A-frag read offset (swizzled)
  const int j8 = 2 * l31 + (lane >> 5);
  const int wread = (j8 ^ ((j8 >> 3) & 7)) * 8;

  f32x16 acc[3];
#pragma unroll
  for (int nt = 0; nt < 3; ++nt)
#pragma unroll
    for (int i = 0; i < 16; ++i) acc[nt][i] = 0.f;

  // prologue loads (cc=0)
  f16x8 rx[4], rw[3];
#pragma unroll
  for (int u = 0; u < 4; ++u)
    rx[u] = *(const f16x8*)(xh + gbase[u]);
#pragma unroll
  for (int u = 0; u < 3; ++u)
    rw[u] = *(const f16x8*)(w + ((0 * 9 + wgt[u]) * 16 + et) * 512 + wgj[u] * 8);

  for (int cc = 0; cc < 16; ++cc) {
    __syncthreads();                              // prev compute done
#pragma unroll
    for (int u = 0; u < 4; ++u)
      if (sok[u]) *(f16x8*)(sx + sgp[u] * 24 + sgo[u]) = rx[u];
#pragma unroll
    for (int u = 0; u < 3; ++u)
      if (wok[u]) *(f16x8*)(sw + wdst[u]) = rw[u];
    __syncthreads();                              // staged visible
    if (cc < 15) {                                // issue next-chunk loads
      int c0 = (cc + 1) * 16;
#pragma unroll
      for (int u = 0; u < 4; ++u)
        rx[u] = *(const f16x8*)(xh + gbase[u] + c0);
#pragma unroll
      for (int u = 0; u < 3; ++u)
        rw[u] = *(const f16x8*)(w + (((cc + 1) * 9 + wgt[u]) * 16 + et) * 512 + wgj[u] * 8);
    }
#pragma unroll
    for (int t = 0; t < 9; ++t) {
      f16x8 aw = *(const f16x8*)(sw + t * 512 + wread);
      const int dy = t / 3, dx = t % 3;
      const int dpo = (dy * 50 + dx) * 24 + koff;
#pragma unroll
      for (int nt = 0; nt < 3; ++nt) {
        f16x8 bh = *(const f16x8*)(sx + pb[nt] * 24 + dpo);
        acc[nt] = mfma16(aw, bh, acc[nt]);
      }
    }
  }

  // epilogue: C/D layout col=lane&31 (=pos), row=(r&3)+8*(r>>2)+4*(lane>>5) (=e)
  const int colh = (lane >> 5) * 4;
#pragma unroll
  for (int nt = 0; nt < 3; ++nt) {
    int n = wvx * 96 + nt * 32 + l31;
    int pos = (y0 + n / 48) * 48 + (n % 48);
    const int jblk = pos >> 5, jl = pos & 31;
    const int jc = pos >> 4, lhv = (pos >> 3) & 1, uv = pos & 7;
#pragma unroll
    for (int g = 0; g < 4; ++g) {
      int eb = e0 + g * 8 + colh;
      f32x4 sb = *(const f32x4*)(bias + eb);
      if (F == 0) {
        f16x4 hq;
#pragma unroll
        for (int j = 0; j < 4; ++j) hq[j] = (f16)(acc[nt][g * 4 + j] + sb[j]);
        *(f16x4*)(oq + ((size_t)b * NN + pos) * NE + eb) = hq;
      } else if (F == 1) {
        f16x4 hk;
#pragma unroll
        for (int j = 0; j < 4; ++j) hk[j] = (f16)(acc[nt][g * 4 + j] + sb[j]);
        // k_f: [b][pos>>5][eb>>4][((eb>>3)&1)*32 + (pos&31)][eb&7 .. +3]
        *(f16x4*)(okf + ((((size_t)b * 72 + jblk) * 32 + (eb >> 4)) * 64 +
                         ((eb >> 3) & 1) * 32 + jl) * 8 + (eb & 7)) = hk;
      } else {
#pragma unroll
        for (int j = 0; j < 4; ++j) {
          int e = eb + j;
          // v_f: [b][e>>5][pos>>4][((pos>>3)&1)*32 + (e&31)][pos&7]
          ovf[((((size_t)b * 16 + (e >> 5)) * 144 + jc) * 64 + lhv * 32 + (e & 31)) * 8 + uv] =
              (f16)(acc[nt][g * 4 + j] + sb[j]);
        }
      }
    }
  }
}

// ---------------- flash attention v7 (j-split x2, L2-resident KV) ----------------
// Grid 1152 jh-major: bid = jh*576 + it*8 + b. b = bid&7 pins XCD; per block
// KV working set = 2.25 MB (L2-fits). Body = R8's lean v4, 9 jt per half.
// Epilogue writes unnormalized po + pm/pl; combine() merges halves.
__global__ __launch_bounds__(256, 3) void attn(
    const f16* __restrict__ qt, const f16* __restrict__ kf,
    const f16* __restrict__ vf, f16* __restrict__ po,
    float* __restrict__ pm, float* __restrict__ pl) {
  __shared__ __align__(16) f16 q_lds[16384];      // 32 frag blocks x 512 f16
  __shared__ __align__(16) f16 sP2[4096];
  __shared__ __align__(16) float s_pmax[128];
  __shared__ __align__(16) float s_psum[128];

  const int tid = threadIdx.x;
  const int lane = tid & 63, wvx = tid >> 6;
  const int l31 = lane & 31, lh = lane >> 5;
  const int bid = blockIdx.x;
  const int b = bid & 7;
  const int t2 = bid >> 3;                        // 0..143
  const int i0 = (t2 % 72) * 32;
  const int jh = t2 / 72;

  // ---- stage q tile (32 x 512) once, into frag-block layout ----
  {
    const f16* qb = qt + ((size_t)b * NN + i0) * NE;
#pragma unroll
    for (int it = 0; it < 8; ++it) {
      int g = it * 256 + tid;
      int row = g >> 6, gr = g & 63;
      f16x8 v = *(const f16x8*)(qb + row * NE + gr * 8);
      *(f16x8*)(q_lds + (gr >> 1) * 512 + (gr & 1) * 256 + row * 8) = v;
    }
  }
  __syncthreads();

  float m_reg = -1e30f, l_reg = 0.f;
  f32x16 O[4];
#pragma unroll
  for (int nt = 0; nt < 4; ++nt)
#pragma unroll
    for (int i = 0; i < 16; ++i) O[nt][i] = 0.f;

  const f16* kfw = kf + (size_t)(b * 72 + jh * 36 + wvx) * 16384 + lane * 8;
  const f16* vfw = vf + (size_t)(b * 16 + wvx * 4) * 73728 + (size_t)jh * 72 * 512 + lane * 8;
  const f16* qlw = q_lds + lane * 8;

  for (int jt = 0; jt < 9; ++jt) {
    // ---- Phase A: S = k.q^T (swapped) — no barriers ----
    const f16* kfl = kfw + (size_t)jt * 4 * 16384;
    f32x16 S0, S1;
#pragma unroll
    for (int i = 0; i < 16; ++i) { S0[i] = 0.f; S1[i] = 0.f; }
    f16x8 kpipe[6];
#pragma unroll
    for (int t = 0; t < 6; ++t) kpipe[t] = *(const f16x8*)(kfl + t * 512);
#pragma unroll
    for (int c = 0; c < 32; ++c) {
      f16x8 ak = kpipe[c % 6];
      if (c + 6 < 32) kpipe[c % 6] = *(const f16x8*)(kfl + (c + 6) * 512);
      f16x8 aq = *(const f16x8*)(qlw + c * 512);
      if (c & 1) S1 = mfma16(ak, aq, S1);
      else       S0 = mfma16(ak, aq, S0);
    }
    f32x16 S;
#pragma unroll
    for (int r = 0; r < 16; ++r) S[r] = S0[r] + S1[r];

    // ---- Phase B: lane-local softmax, 2 barriers ----
    float wmax = S[0];
#pragma unroll
    for (int r = 1; r < 16; ++r) wmax = fmaxf(wmax, S[r]);
    wmax = fmaxf(wmax, __shfl_xor(wmax, 32, 64));
    if (lane < 32) s_pmax[l31 * 4 + wvx] = wmax;
    __syncthreads();                              // barrier 1 (also fences sP2)
    f32x4 pm4 = *(const f32x4*)(s_pmax + l31 * 4);
    float gmax = fmaxf(fmaxf(pm4[0], pm4[1]), fmaxf(pm4[2], pm4[3]));
    float mnew = fmaxf(m_reg, gmax);
    float alpha = __expf(m_reg - mnew);
    m_reg = mnew;

    f16 ph[16];
    float psum = 0.f;
#pragma unroll
    for (int r = 0; r < 16; ++r) {
      f16 p = (f16)__expf(S[r] - mnew);
      ph[r] = p;
      psum += (float)p;
    }
    union Q4 { f16x4 h; int i2[2]; };
    Q4 q4[4];
#pragma unroll
    for (int t = 0; t < 4; ++t)
#pragma unroll
      for (int u = 0; u < 4; ++u) q4[t].h[u] = ph[t * 4 + u];
#pragma unroll
    for (int ks = 0; ks < 2; ++ks) {
      Q4 t1a, t2a;
      t1a.i2[0] = __shfl_xor(q4[2 * ks + 1].i2[0], 32, 64);
      t1a.i2[1] = __shfl_xor(q4[2 * ks + 1].i2[1], 32, 64);
      t2a.i2[0] = __shfl_xor(q4[2 * ks].i2[0], 32, 64);
      t2a.i2[1] = __shfl_xor(q4[2 * ks].i2[1], 32, 64);
      f16x4 first  = lh ? t1a.h : q4[2 * ks].h;
      f16x4 second = lh ? q4[2 * ks + 1].h : t2a.h;
      f16x8 frag;
#pragma unroll
      for (int u = 0; u < 4; ++u) { frag[u] = first[u]; frag[4 + u] = second[u]; }
      *(f16x8*)(sP2 + ((wvx * 2 + ks) * 64 + lane) * 8) = frag;
    }
    psum += __shfl_xor(psum, 32, 64);
    if (lane < 32) s_psum[l31 * 4 + wvx] = psum;
#pragma unroll
    for (int nt = 0; nt < 4; ++nt)
#pragma unroll
      for (int r = 0; r < 16; ++r) O[nt][r] *= alpha;
    __syncthreads();                              // barrier 2 (P + sums visible)
    f32x4 ps4 = *(const f32x4*)(s_psum + l31 * 4);
    l_reg = l_reg * alpha + (ps4[0] + ps4[1] + ps4[2] + ps4[3]);

    // ---- Phase C: O += V.P — no barriers ----
    const f16* vfl = vfw + (size_t)jt * 8 * 512;
    f16x8 vpipe[6];
#pragma unroll
    for (int t = 0; t < 6; ++t) {
      int nt = t & 3, cg = t >> 2;
      vpipe[t] = *(const f16x8*)(vfl + (size_t)nt * 73728 + cg * 512);
    }
    f16x8 apc = *(const f16x8*)(sP2 + (0 * 64 + lane) * 8);
    f16x8 apn = *(const f16x8*)(sP2 + (1 * 64 + lane) * 8);
#pragma unroll
    for (int c = 0; c < 32; ++c) {
      int nt = c & 3, cg = c >> 2;
      f16x8 av = vpipe[c % 6];
      if (c + 6 < 32) {
        int nt2 = (c + 6) & 3, cg2 = (c + 6) >> 2;
        vpipe[c % 6] = *(const f16x8*)(vfl + (size_t)nt2 * 73728 + cg2 * 512);
      }
      O[nt] = mfma16(av, apc, O[nt]);
      if (nt == 3) {
        apc = apn;
        if (cg + 2 < 8) apn = *(const f16x8*)(sP2 + ((cg + 2) * 64 + lane) * 8);
      }
    }
  }

  // ---- epilogue: unnormalized po + m/l partials ----
  if (tid < 32) {
    pm[(jh * NB + b) * NN + i0 + tid] = m_reg;
    pl[(jh * NB + b) * NN + i0 + tid] = l_reg;
  }
  const size_t pobase = ((size_t)(jh * NB + b) * NE) * NN;
  const int ii = i0 + l31;
#pragma unroll
  for (int nt = 0; nt < 4; ++nt) {
    const int ebase = wvx * 128 + nt * 32;
#pragma unroll
    for (int r = 0; r < 16; ++r) {
      int el = (r & 3) + 8 * (r >> 2) + 4 * lh;
      po[pobase + (size_t)(ebase + el) * NN + ii] = (f16)O[nt][r];
    }
  }
}

// ---------------- combine: merge 2 j-halves, divide, add v (from v_f) --------
__global__ void combine(const f16* __restrict__ po, const float* __restrict__ pm,
                        const float* __restrict__ pl, const f16* __restrict__ vf,
                        float* __restrict__ out) {
  int id = blockIdx.x * 256 + threadIdx.x;        // NB*NE*NN/4
  int base = id * 4;
  int i  = base % NN;
  int eb = base / NN;                             // b*NE + e
  int b  = eb >> 9;
  int e  = eb & 511;
  const size_t H = (size_t)NB * NE * NN;
  f32x4 m0 = *(const f32x4*)(pm + b * NN + i);
  f32x4 m1 = *(const f32x4*)(pm + NB * NN + b * NN + i);
  f32x4 l0 = *(const f32x4*)(pl + b * NN + i);
  f32x4 l1 = *(const f32x4*)(pl + NB * NN + b * NN + i);
  f16x4 a0 = *(const f16x4*)(po + (size_t)eb * NN + i);
  f16x4 a1 = *(const f16x4*)(po + H + (size_t)eb * NN + i);
  // v residual from v_f frag blocks: i..i+3 contiguous (i&7 in {0,4})
  f16x4 vv = *(const f16x4*)(vf + ((((size_t)(b * 16 + (e >> 5))) * 144 + (i >> 4)) * 64 +
                                   ((i >> 3) & 1) * 32 + (e & 31)) * 8 + (i & 7));
  f32x4 res;
#pragma unroll
  for (int j = 0; j < 4; ++j) {
    float m = fmaxf(m0[j], m1[j]);
    float w0 = __expf(m0[j] - m), w1 = __expf(m1[j] - m);
    float l = w0 * l0[j] + w1 * l1[j];
    res[j] = (w0 * (float)a0[j] + w1 * (float)a1[j]) / l + (float)vv[j];
  }
  *(f32x4*)(out + (size_t)eb * NN + i) = res;
}

// ---------------- launch ----------------
extern "C" void kernel_launch(void* const* d_in, const int* in_sizes, int n_in,
                              void* d_out, int out_size, void* d_ws, size_t ws_size,
                              hipStream_t stream) {
  const float* feat = (const float*)d_in[0];
  const float* Wq = (const float*)d_in[1];
  const float* bq = (const float*)d_in[2];
  const float* Wk = (const float*)d_in[3];
  const float* bk = (const float*)d_in[4];
  const float* Wv = (const float*)d_in[5];
  const float* bv = (const float*)d_in[6];
  float* out = (float*)d_out;

  char* ws = (char*)d_ws;
  size_t off = 0;
  auto alloc = [&](size_t bytes) {
    void* p = ws + off;
    off += (bytes + 255) & ~(size_t)255;
    return p;
  };
  const size_t FP = (size_t)NB * HP * HP * NC;     // 5,120,000
  const size_t WP = (size_t)9 * NE * NC;           // 1,179,648
  const size_t QP = (size_t)NB * NN * NE;          // 9,437,184
  f16* fp  = (f16*)alloc(FP * 2);
  f16* wq  = (f16*)alloc(WP * 2);
  f16* wk  = (f16*)alloc(WP * 2);
  f16* wv  = (f16*)alloc(WP * 2);
  f16* q_t = (f16*)alloc(QP * 2);
  f16* k_f = (f16*)alloc(QP * 2);
  f16* v_f = (f16*)alloc(QP * 2);
  f16* po  = (f16*)alloc(2 * QP * 2);              // 37.7 MB partial O
  float* pm = (float*)alloc(2 * (size_t)NB * NN * 4);
  float* pl = (float*)alloc(2 * (size_t)NB * NN * 4);

  pack_feat<<<dim3(NB, HP), dim3(256), 0, stream>>>(feat, fp);
  pack_w<<<dim3(WP / 256), dim3(256), 0, stream>>>(Wq, Wk, Wv, wq, wk, wv);

  conv3_all<<<dim3(2304), dim3(256), 0, stream>>>(
      fp, wq, wk, wv, bq, bk, bv, q_t, k_f, v_f);

  attn<<<dim3(1152), dim3(256), 0, stream>>>(q_t, k_f, v_f, po, pm, pl);
  combine<<<dim3((NB * NE * NN / 4) / 256), dim3(256), 0, stream>>>(po, pm, pl, v_f, out);
}

// Round 11
// 381.564 us; speedup vs baseline: 1.1724x; 1.1724x over previous
//
#include <hip/hip_runtime.h>

// ConvSA: B=8, C=256, H=W=48 (N=2304), E=512.
// out[b,e,i] = sum_j softmax_j(q[:,i].k[:,j]) * v[e,j] + v[e,i]
// R11: attn v8 — MLP round. R3/R9/R10 invariant: dur pinned at ~182 while
// waves/CU x pipe-depth stayed ~48 => MLP-throughput-bound. Fix:
//  - single-S MFMA chain (dependent same-acc MFMAs run at full rate, m119)
//    -> acc 112->80, total regs ~150 <= 170 -> 3 waves/SIMD legal.
//  - pipes depth 6->8 with the freed regs. MLP/CU 48 -> 96.
//  - no j-split (grid 576, all resident at 2.25/CU avg), no combine.
//  - defer-max exact skip (__all(mnew==m_reg), R4/R6-verified).
//  - conv3_all + packs: R10-verified, unchanged.

typedef _Float16 f16;
typedef _Float16 f16x4 __attribute__((ext_vector_type(4)));
typedef _Float16 f16x8 __attribute__((ext_vector_type(8)));
typedef float    f32x4  __attribute__((ext_vector_type(4)));
typedef float    f32x16 __attribute__((ext_vector_type(16)));

__device__ __forceinline__ f32x16 mfma16(f16x8 a, f16x8 b, f32x16 c) {
  return __builtin_amdgcn_mfma_f32_32x32x16_f16(a, b, c, 0, 0, 0);
}

__device__ __forceinline__ f16x8 f16x8_zero() {
  f16x8 z;
#pragma unroll
  for (int j = 0; j < 8; ++j) z[j] = (f16)0.f;
  return z;
}

#define NB   8
#define NC   256
#define NH   48
#define NN   2304     // 48*48
#define NE   512
#define HP   50       // padded H/W

// ---------------- pack kernels ----------------

// feat NCHW fp32 -> zero-padded NHWC [b][50][50][256] fp16 (R9-verified).
__global__ void pack_feat(const float* __restrict__ x, f16* __restrict__ p) {
  __shared__ f16 tx[48 * 258];
  const int b = blockIdx.x, yp = blockIdx.y;
  const int tid = threadIdx.x;
  f16* prow = p + ((size_t)(b * HP + yp) * HP) * NC;

  if (yp == 0 || yp == HP - 1) {
    for (int i = tid; i < 1600; i += 256)
      *(f16x8*)(prow + i * 8) = f16x8_zero();
    return;
  }
  const int y = yp - 1;
#pragma unroll 4
  for (int it = 0; it < 64; ++it) {
    int i = it * 256 + tid;
    int xsl = i & 63, c = i >> 6;
    if (xsl < 48) {
      float v = x[((b * NC + c) * NH + y) * NH + xsl];
      tx[xsl * 258 + c] = (f16)v;
    }
  }
  __syncthreads();
#pragma unroll
  for (int it = 0; it < 6; ++it) {
    int xq = (tid >> 5) + it * 8;
    int c0 = (tid & 31) * 8;
    f16x8 v = *(const f16x8*)(tx + xq * 258 + c0);
    *(f16x8*)(prow + (xq + 1) * NC + c0) = v;
  }
  if (tid < 64) {
    int xp = (tid >> 5) * (HP - 1);
    int c0 = (tid & 31) * 8;
    *(f16x8*)(prow + xp * NC + c0) = f16x8_zero();
  }
}

// W OIHW [512][256][3][3] fp32 -> A-frag blocks:
// [cc 16][t 9][et 16] x (el 32 x cl 16) contiguous 512-f16 (1 KB) blocks.
__global__ void pack_w(const float* __restrict__ wq, const float* __restrict__ wk,
                       const float* __restrict__ wv,
                       f16* __restrict__ oq, f16* __restrict__ ok,
                       f16* __restrict__ ov) {
  int idx = blockIdx.x * 256 + threadIdx.x;       // 9*512*256
  int c = idx & 255;
  int r = idx >> 8;
  int e = r & 511; int t = r >> 9;
  int src = (e * NC + c) * 9 + t;
  int cc = c >> 4, cl = c & 15, et = e >> 5, el = e & 31;
  int dst = ((cc * 9 + t) * 16 + et) * 512 + el * 16 + cl;
  oq[dst] = (f16)wq[src];
  ok[dst] = (f16)wk[src];
  ov[dst] = (f16)wv[src];
}

// ---------------- conv3x3: b-pinned grid, W via LDS (R10-verified) ----------------
__global__ __launch_bounds__(256, 3) void conv3_all(
    const f16* __restrict__ xh,
    const f16* __restrict__ wq, const f16* __restrict__ wk,
    const f16* __restrict__ wv,
    const float* __restrict__ bq, const float* __restrict__ bk,
    const float* __restrict__ bv,
    f16* __restrict__ oq, f16* __restrict__ okf, f16* __restrict__ ovf) {
  __shared__ __align__(16) f16 sx[12000];         // 24 KB
  __shared__ __align__(16) f16 sw[4608];          // 9 KB

  const int tid = threadIdx.x;
  const int lane = tid & 63, wvx = tid >> 6;
  const int l31 = lane & 31;
  const int koff = (lane >> 5) * 8;
  const int bid = blockIdx.x;
  const int b = bid & 7;
  int r = bid >> 3;                               // 0..287
  const int strip = r % 6; r /= 6;                // 0..47
  const int et = r & 15, F = r >> 4;
  const int e0 = et * 32;
  const int y0 = strip * 8;
  const f16* w = (F == 0) ? wq : (F == 1) ? wk : wv;
  const float* bias = (F == 0) ? bq : (F == 1) ? bk : bv;

  int pb[3];
#pragma unroll
  for (int nt = 0; nt < 3; ++nt) {
    int n = wvx * 96 + nt * 32 + l31;
    pb[nt] = (n / 48) * 50 + (n % 48);
  }

  int sgp[4], sgo[4]; bool sok[4]; int gbase[4];
#pragma unroll
  for (int u = 0; u < 4; ++u) {
    int g = u * 256 + tid;
    sok[u] = (g < 1000);
    int gg = sok[u] ? g : 999;
    sgp[u] = gg >> 1; sgo[u] = (gg & 1) * 8;
    int row = sgp[u] / 50, xx = sgp[u] % 50;
    gbase[u] = ((b * HP + y0 + row) * HP + xx) * NC + sgo[u];
  }
  int wgt[3], wgj[3], wdst[3]; bool wok[3];
#pragma unroll
  for (int u = 0; u < 3; ++u) {
    int g = u * 256 + tid;
    wok[u] = (g < 576);
    int gg = wok[u] ? g : 575;
    wgt[u] = gg >> 6; wgj[u] = gg & 63;
    int wjs = wgj[u] ^ ((wgj[u] >> 3) & 7);
    wdst[u] = wgt[u] * 512 + wjs * 8;
  }
  const int j8 = 2 * l31 + (lane >> 5);
  const int wread = (j8 ^ ((j8 >> 3) & 7)) * 8;

  f32x16 acc[3];
#pragma unroll
  for (int nt = 0; nt < 3; ++nt)
#pragma unroll
    for (int i = 0; i < 16; ++i) acc[nt][i] = 0.f;

  f16x8 rx[4], rw[3];
#pragma unroll
  for (int u = 0; u < 4; ++u)
    rx[u] = *(const f16x8*)(xh + gbase[u]);
#pragma unroll
  for (int u = 0; u < 3; ++u)
    rw[u] = *(const f16x8*)(w + ((0 * 9 + wgt[u]) * 16 + et) * 512 + wgj[u] * 8);

  for (int cc = 0; cc < 16; ++cc) {
    __syncthreads();
#pragma unroll
    for (int u = 0; u < 4; ++u)
      if (sok[u]) *(f16x8*)(sx + sgp[u] * 24 + sgo[u]) = rx[u];
#pragma unroll
    for (int u = 0; u < 3; ++u)
      if (wok[u]) *(f16x8*)(sw + wdst[u]) = rw[u];
    __syncthreads();
    if (cc < 15) {
      int c0 = (cc + 1) * 16;
#pragma unroll
      for (int u = 0; u < 4; ++u)
        rx[u] = *(const f16x8*)(xh + gbase[u] + c0);
#pragma unroll
      for (int u = 0; u < 3; ++u)
        rw[u] = *(const f16x8*)(w + (((cc + 1) * 9 + wgt[u]) * 16 + et) * 512 + wgj[u] * 8);
    }
#pragma unroll
    for (int t = 0; t < 9; ++t) {
      f16x8 aw = *(const f16x8*)(sw + t * 512 + wread);
      const int dy = t / 3, dx = t % 3;
      const int dpo = (dy * 50 + dx) * 24 + koff;
#pragma unroll
      for (int nt = 0; nt < 3; ++nt) {
        f16x8 bh = *(const f16x8*)(sx + pb[nt] * 24 + dpo);
        acc[nt] = mfma16(aw, bh, acc[nt]);
      }
    }
  }

  const int colh = (lane >> 5) * 4;
#pragma unroll
  for (int nt = 0; nt < 3; ++nt) {
    int n = wvx * 96 + nt * 32 + l31;
    int pos = (y0 + n / 48) * 48 + (n % 48);
    const int jblk = pos >> 5, jl = pos & 31;
    const int jc = pos >> 4, lhv = (pos >> 3) & 1, uv = pos & 7;
#pragma unroll
    for (int g = 0; g < 4; ++g) {
      int eb = e0 + g * 8 + colh;
      f32x4 sb = *(const f32x4*)(bias + eb);
      if (F == 0) {
        f16x4 hq;
#pragma unroll
        for (int j = 0; j < 4; ++j) hq[j] = (f16)(acc[nt][g * 4 + j] + sb[j]);
        *(f16x4*)(oq + ((size_t)b * NN + pos) * NE + eb) = hq;
      } else if (F == 1) {
        f16x4 hk;
#pragma unroll
        for (int j = 0; j < 4; ++j) hk[j] = (f16)(acc[nt][g * 4 + j] + sb[j]);
        *(f16x4*)(okf + ((((size_t)b * 72 + jblk) * 32 + (eb >> 4)) * 64 +
                         ((eb >> 3) & 1) * 32 + jl) * 8 + (eb & 7)) = hk;
      } else {
#pragma unroll
        for (int j = 0; j < 4; ++j) {
          int e = eb + j;
          ovf[((((size_t)b * 16 + (e >> 5)) * 144 + jc) * 64 + lhv * 32 + (e & 31)) * 8 + uv] =
              (f16)(acc[nt][g * 4 + j] + sb[j]);
        }
      }
    }
  }
}

// ---------------- flash attention v8 (single-S chain, depth-8, 3 waves/SIMD) ----
// Grid 576: b = bid&7 (XCD pin), i-tile = bid>>3 (32 rows). 18 jt of 128 j.
// acc = S(16) + O(64) = 80; total regs ~150 <= 170 -> 3 waves/SIMD.
__global__ __launch_bounds__(256, 3) void attn(
    const f16* __restrict__ qt, const f16* __restrict__ kf,
    const f16* __restrict__ vf, float* __restrict__ out) {
  __shared__ __align__(16) f16 q_lds[16384];      // 32 frag blocks x 512 f16
  __shared__ __align__(16) f16 sP2[4096];         // 8 chunks x 64 lanes x 8 f16
  __shared__ __align__(16) float s_pmax[128];
  __shared__ __align__(16) float s_psum[128];

  const int tid = threadIdx.x;
  const int lane = tid & 63, wvx = tid >> 6;
  const int l31 = lane & 31, lh = lane >> 5;
  const int bid = blockIdx.x;
  const int b = bid & 7;
  const int i0 = (bid >> 3) * 32;

  // ---- stage q tile (32 x 512) once, into frag-block layout ----
  {
    const f16* qb = qt + ((size_t)b * NN + i0) * NE;
#pragma unroll
    for (int it = 0; it < 8; ++it) {
      int g = it * 256 + tid;
      int row = g >> 6, gr = g & 63;
      f16x8 v = *(const f16x8*)(qb + row * NE + gr * 8);
      *(f16x8*)(q_lds + (gr >> 1) * 512 + (gr & 1) * 256 + row * 8) = v;
    }
  }
  __syncthreads();

  float m_reg = -1e30f, l_reg = 0.f;
  f32x16 O[4];
#pragma unroll
  for (int nt = 0; nt < 4; ++nt)
#pragma unroll
    for (int i = 0; i < 16; ++i) O[nt][i] = 0.f;

  const f16* kfw = kf + (size_t)(b * 72 + wvx) * 16384 + lane * 8;
  const f16* vfw = vf + (size_t)(b * 16 + wvx * 4) * 73728 + lane * 8;
  const f16* qlw = q_lds + lane * 8;

  for (int jt = 0; jt < 18; ++jt) {
    // ---- Phase A: S = k.q^T, single acc chain, depth-8 k stream ----
    const f16* kfl = kfw + (size_t)jt * 4 * 16384;
    f32x16 S;
#pragma unroll
    for (int i = 0; i < 16; ++i) S[i] = 0.f;
    f16x8 kpipe[8];
#pragma unroll
    for (int t = 0; t < 8; ++t) kpipe[t] = *(const f16x8*)(kfl + t * 512);
#pragma unroll
    for (int c = 0; c < 32; ++c) {
      f16x8 ak = kpipe[c & 7];
      if (c + 8 < 32) kpipe[c & 7] = *(const f16x8*)(kfl + (c + 8) * 512);
      f16x8 aq = *(const f16x8*)(qlw + c * 512);
      S = mfma16(ak, aq, S);
    }
    // lane (i=l31, h=lh) holds S[i][j_local = (r&3)+8*(r>>2)+4*lh].

    // ---- Phase B: lane-local softmax, 2 barriers ----
    float wmax = S[0];
#pragma unroll
    for (int r = 1; r < 16; ++r) wmax = fmaxf(wmax, S[r]);
    wmax = fmaxf(wmax, __shfl_xor(wmax, 32, 64));
    if (lane < 32) s_pmax[l31 * 4 + wvx] = wmax;
    __syncthreads();                              // barrier 1 (also fences sP2)
    f32x4 pm4 = *(const f32x4*)(s_pmax + l31 * 4);
    float gmax = fmaxf(fmaxf(pm4[0], pm4[1]), fmaxf(pm4[2], pm4[3]));
    float mnew = fmaxf(m_reg, gmax);
    float alpha = 1.f;
    if (!__all(mnew == m_reg)) {                  // defer-max exact skip
      alpha = __expf(m_reg - mnew);
      m_reg = mnew;
#pragma unroll
      for (int nt = 0; nt < 4; ++nt)
#pragma unroll
        for (int r = 0; r < 16; ++r) O[nt][r] *= alpha;
    }

    f16 ph[16];
    float psum = 0.f;
#pragma unroll
    for (int r = 0; r < 16; ++r) {
      f16 p = (f16)__expf(S[r] - m_reg);
      ph[r] = p;
      psum += (float)p;
    }
    // pack quads -> B-frags via cross-half exchange, write sP2
    union Q4 { f16x4 h; int i2[2]; };
    Q4 q4[4];
#pragma unroll
    for (int t = 0; t < 4; ++t)
#pragma unroll
      for (int u = 0; u < 4; ++u) q4[t].h[u] = ph[t * 4 + u];
#pragma unroll
    for (int ks = 0; ks < 2; ++ks) {
      Q4 t1, t2;
      t1.i2[0] = __shfl_xor(q4[2 * ks + 1].i2[0], 32, 64);
      t1.i2[1] = __shfl_xor(q4[2 * ks + 1].i2[1], 32, 64);
      t2.i2[0] = __shfl_xor(q4[2 * ks].i2[0], 32, 64);
      t2.i2[1] = __shfl_xor(q4[2 * ks].i2[1], 32, 64);
      f16x4 first  = lh ? t1.h : q4[2 * ks].h;
      f16x4 second = lh ? q4[2 * ks + 1].h : t2.h;
      f16x8 frag;
#pragma unroll
      for (int u = 0; u < 4; ++u) { frag[u] = first[u]; frag[4 + u] = second[u]; }
      *(f16x8*)(sP2 + ((wvx * 2 + ks) * 64 + lane) * 8) = frag;
    }
    psum += __shfl_xor(psum, 32, 64);
    if (lane < 32) s_psum[l31 * 4 + wvx] = psum;
    __syncthreads();                              // barrier 2 (P + sums visible)
    f32x4 ps4 = *(const f32x4*)(s_psum + l31 * 4);
    l_reg = l_reg * alpha + (ps4[0] + ps4[1] + ps4[2] + ps4[3]);

    // ---- Phase C: O += V.P, depth-8 v stream — no barriers ----
    const f16* vfl = vfw + (size_t)jt * 8 * 512;
    f16x8 vpipe[8];
#pragma unroll
    for (int t = 0; t < 8; ++t) {
      int nt = t & 3, cg = t >> 2;
      vpipe[t] = *(const f16x8*)(vfl + (size_t)nt * 73728 + cg * 512);
    }
    f16x8 apc = *(const f16x8*)(sP2 + (0 * 64 + lane) * 8);
    f16x8 apn = *(const f16x8*)(sP2 + (1 * 64 + lane) * 8);
#pragma unroll
    for (int c = 0; c < 32; ++c) {
      int nt = c & 3, cg = c >> 2;
      f16x8 av = vpipe[c & 7];
      if (c + 8 < 32) {
        int c2 = c + 8, nt2 = c2 & 3, cg2 = c2 >> 2;
        vpipe[c & 7] = *(const f16x8*)(vfl + (size_t)nt2 * 73728 + cg2 * 512);
      }
      O[nt] = mfma16(av, apc, O[nt]);
      if (nt == 3) {
        apc = apn;
        if (cg + 2 < 8) apn = *(const f16x8*)(sP2 + ((cg + 2) * 64 + lane) * 8);
      }
    }
  }

  // ---- epilogue: per-lane normalize + v residual, direct coalesced stores ----
  float inv = 1.0f / l_reg;
  const int ii = i0 + l31;
  const int jcR = ii >> 4, lhR = (ii >> 3) & 1, uR = ii & 7;
#pragma unroll
  for (int nt = 0; nt < 4; ++nt) {
    const f16* vres = vf + ((((size_t)(b * 16 + wvx * 4 + nt)) * 144 + jcR) * 64 + lhR * 32) * 8 + uR;
    const int ebase = wvx * 128 + nt * 32;
#pragma unroll
    for (int r = 0; r < 16; ++r) {
      int el = (r & 3) + 8 * (r >> 2) + 4 * lh;
      float rv = (float)vres[el * 8];
      out[((size_t)b * NE + ebase + el) * NN + ii] = O[nt][r] * inv + rv;
    }
  }
}

// ---------------- launch ----------------
extern "C" void kernel_launch(void* const* d_in, const int* in_sizes, int n_in,
                              void* d_out, int out_size, void* d_ws, size_t ws_size,
                              hipStream_t stream) {
  const float* feat = (const float*)d_in[0];
  const float* Wq = (const float*)d_in[1];
  const float* bq = (const float*)d_in[2];
  const float* Wk = (const float*)d_in[3];
  const float* bk = (const float*)d_in[4];
  const float* Wv = (const float*)d_in[5];
  const float* bv = (const float*)d_in[6];
  float* out = (float*)d_out;

  char* ws = (char*)d_ws;
  size_t off = 0;
  auto alloc = [&](size_t bytes) {
    void* p = ws + off;
    off += (bytes + 255) & ~(size_t)255;
    return p;
  };
  const size_t FP = (size_t)NB * HP * HP * NC;     // 5,120,000
  const size_t WP = (size_t)9 * NE * NC;           // 1,179,648
  const size_t QP = (size_t)NB * NN * NE;          // 9,437,184
  f16* fp  = (f16*)alloc(FP * 2);
  f16* wq  = (f16*)alloc(WP * 2);
  f16* wk  = (f16*)alloc(WP * 2);
  f16* wv  = (f16*)alloc(WP * 2);
  f16* q_t = (f16*)alloc(QP * 2);
  f16* k_f = (f16*)alloc(QP * 2);
  f16* v_f = (f16*)alloc(QP * 2);

  pack_feat<<<dim3(NB, HP), dim3(256), 0, stream>>>(feat, fp);
  pack_w<<<dim3(WP / 256), dim3(256), 0, stream>>>(Wq, Wk, Wv, wq, wk, wv);

  conv3_all<<<dim3(2304), dim3(256), 0, stream>>>(
      fp, wq, wk, wv, bq, bk, bv, q_t, k_f, v_f);

  attn<<<dim3(576), dim3(256), 0, stream>>>(q_t, k_f, v_f, out);
}

// Round 12
// 359.748 us; speedup vs baseline: 1.2435x; 1.0606x over previous
//
#include <hip/hip_runtime.h>

// ConvSA: B=8, C=256, H=W=48 (N=2304), E=512.
// out[b,e,i] = sum_j softmax_j(q[:,i].k[:,j]) * v[e,j] + v[e,i]
// R12 (on R11's 381us):
//  - conv3_all: launch_bounds(256,4) — regs ~108 <= 128, LDS 33KB*4 <= 160KB
//    -> 16 waves/CU to overlap LDS+staging against MFMA (was 44% MfmaUtil).
//  - attn v9: S0/S1 split (Phase A was a 32-long DEPENDENT same-acc MFMA
//    chain; two interleaved 16-chains restore issue rate). acc 96 + arch ~68
//    = ~164 <= 170, still (256,3)-legal (R3 precedent: same acc, VGPR 80).
//  - pack_w: thread-per-(e,c), 9-float contiguous reads (coalesced waves).

typedef _Float16 f16;
typedef _Float16 f16x4 __attribute__((ext_vector_type(4)));
typedef _Float16 f16x8 __attribute__((ext_vector_type(8)));
typedef float    f32x4  __attribute__((ext_vector_type(4)));
typedef float    f32x16 __attribute__((ext_vector_type(16)));

__device__ __forceinline__ f32x16 mfma16(f16x8 a, f16x8 b, f32x16 c) {
  return __builtin_amdgcn_mfma_f32_32x32x16_f16(a, b, c, 0, 0, 0);
}

__device__ __forceinline__ f16x8 f16x8_zero() {
  f16x8 z;
#pragma unroll
  for (int j = 0; j < 8; ++j) z[j] = (f16)0.f;
  return z;
}

#define NB   8
#define NC   256
#define NH   48
#define NN   2304     // 48*48
#define NE   512
#define HP   50       // padded H/W

// ---------------- pack kernels ----------------

// feat NCHW fp32 -> zero-padded NHWC [b][50][50][256] fp16 (R9-verified).
__global__ void pack_feat(const float* __restrict__ x, f16* __restrict__ p) {
  __shared__ f16 tx[48 * 258];
  const int b = blockIdx.x, yp = blockIdx.y;
  const int tid = threadIdx.x;
  f16* prow = p + ((size_t)(b * HP + yp) * HP) * NC;

  if (yp == 0 || yp == HP - 1) {
    for (int i = tid; i < 1600; i += 256)
      *(f16x8*)(prow + i * 8) = f16x8_zero();
    return;
  }
  const int y = yp - 1;
#pragma unroll 4
  for (int it = 0; it < 64; ++it) {
    int i = it * 256 + tid;
    int xsl = i & 63, c = i >> 6;
    if (xsl < 48) {
      float v = x[((b * NC + c) * NH + y) * NH + xsl];
      tx[xsl * 258 + c] = (f16)v;
    }
  }
  __syncthreads();
#pragma unroll
  for (int it = 0; it < 6; ++it) {
    int xq = (tid >> 5) + it * 8;
    int c0 = (tid & 31) * 8;
    f16x8 v = *(const f16x8*)(tx + xq * 258 + c0);
    *(f16x8*)(prow + (xq + 1) * NC + c0) = v;
  }
  if (tid < 64) {
    int xp = (tid >> 5) * (HP - 1);
    int c0 = (tid & 31) * 8;
    *(f16x8*)(prow + xp * NC + c0) = f16x8_zero();
  }
}

// W OIHW [512][256][3][3] fp32 -> A-frag blocks. Thread-per-(e,c):
// 9 contiguous floats per thread -> wave reads 2304 contiguous bytes.
__global__ void pack_w(const float* __restrict__ wq, const float* __restrict__ wk,
                       const float* __restrict__ wv,
                       f16* __restrict__ oq, f16* __restrict__ ok,
                       f16* __restrict__ ov) {
  int idx = blockIdx.x * 256 + threadIdx.x;       // 512*256 (e,c) pairs
  int c = idx & 255, e = idx >> 8;
  int cc = c >> 4, cl = c & 15, et = e >> 5, el = e & 31;
  const float* sq = wq + (size_t)idx * 9;
  const float* sk = wk + (size_t)idx * 9;
  const float* sv = wv + (size_t)idx * 9;
#pragma unroll
  for (int t = 0; t < 9; ++t) {
    int dst = ((cc * 9 + t) * 16 + et) * 512 + el * 16 + cl;
    oq[dst] = (f16)sq[t];
    ok[dst] = (f16)sk[t];
    ov[dst] = (f16)sv[t];
  }
}

// ---------------- conv3x3: b-pinned grid, W via LDS, 4 blocks/CU ----------------
__global__ __launch_bounds__(256, 4) void conv3_all(
    const f16* __restrict__ xh,
    const f16* __restrict__ wq, const f16* __restrict__ wk,
    const f16* __restrict__ wv,
    const float* __restrict__ bq, const float* __restrict__ bk,
    const float* __restrict__ bv,
    f16* __restrict__ oq, f16* __restrict__ okf, f16* __restrict__ ovf) {
  __shared__ __align__(16) f16 sx[12000];         // 24 KB
  __shared__ __align__(16) f16 sw[4608];          // 9 KB

  const int tid = threadIdx.x;
  const int lane = tid & 63, wvx = tid >> 6;
  const int l31 = lane & 31;
  const int koff = (lane >> 5) * 8;
  const int bid = blockIdx.x;
  const int b = bid & 7;
  int r = bid >> 3;                               // 0..287
  const int strip = r % 6; r /= 6;                // 0..47
  const int et = r & 15, F = r >> 4;
  const int e0 = et * 32;
  const int y0 = strip * 8;
  const f16* w = (F == 0) ? wq : (F == 1) ? wk : wv;
  const float* bias = (F == 0) ? bq : (F == 1) ? bk : bv;

  int pb[3];
#pragma unroll
  for (int nt = 0; nt < 3; ++nt) {
    int n = wvx * 96 + nt * 32 + l31;
    pb[nt] = (n / 48) * 50 + (n % 48);
  }

  int sgp[4], sgo[4]; bool sok[4]; int gbase[4];
#pragma unroll
  for (int u = 0; u < 4; ++u) {
    int g = u * 256 + tid;
    sok[u] = (g < 1000);
    int gg = sok[u] ? g : 999;
    sgp[u] = gg >> 1; sgo[u] = (gg & 1) * 8;
    int row = sgp[u] / 50, xx = sgp[u] % 50;
    gbase[u] = ((b * HP + y0 + row) * HP + xx) * NC + sgo[u];
  }
  int wgt[3], wgj[3], wdst[3]; bool wok[3];
#pragma unroll
  for (int u = 0; u < 3; ++u) {
    int g = u * 256 + tid;
    wok[u] = (g < 576);
    int gg = wok[u] ? g : 575;
    wgt[u] = gg >> 6; wgj[u] = gg & 63;
    int wjs = wgj[u] ^ ((wgj[u] >> 3) & 7);
    wdst[u] = wgt[u] * 512 + wjs * 8;
  }
  const int j8 = 2 * l31 + (lane >> 5);
  const int wread = (j8 ^ ((j8 >> 3) & 7)) * 8;

  f32x16 acc[3];
#pragma unroll
  for (int nt = 0; nt < 3; ++nt)
#pragma unroll
    for (int i = 0; i < 16; ++i) acc[nt][i] = 0.f;

  f16x8 rx[4], rw[3];
#pragma unroll
  for (int u = 0; u < 4; ++u)
    rx[u] = *(const f16x8*)(xh + gbase[u]);
#pragma unroll
  for (int u = 0; u < 3; ++u)
    rw[u] = *(const f16x8*)(w + ((0 * 9 + wgt[u]) * 16 + et) * 512 + wgj[u] * 8);

  for (int cc = 0; cc < 16; ++cc) {
    __syncthreads();
#pragma unroll
    for (int u = 0; u < 4; ++u)
      if (sok[u]) *(f16x8*)(sx + sgp[u] * 24 + sgo[u]) = rx[u];
#pragma unroll
    for (int u = 0; u < 3; ++u)
      if (wok[u]) *(f16x8*)(sw + wdst[u]) = rw[u];
    __syncthreads();
    if (cc < 15) {
      int c0 = (cc + 1) * 16;
#pragma unroll
      for (int u = 0; u < 4; ++u)
        rx[u] = *(const f16x8*)(xh + gbase[u] + c0);
#pragma unroll
      for (int u = 0; u < 3; ++u)
        rw[u] = *(const f16x8*)(w + (((cc + 1) * 9 + wgt[u]) * 16 + et) * 512 + wgj[u] * 8);
    }
#pragma unroll
    for (int t = 0; t < 9; ++t) {
      f16x8 aw = *(const f16x8*)(sw + t * 512 + wread);
      const int dy = t / 3, dx = t % 3;
      const int dpo = (dy * 50 + dx) * 24 + koff;
#pragma unroll
      for (int nt = 0; nt < 3; ++nt) {
        f16x8 bh = *(const f16x8*)(sx + pb[nt] * 24 + dpo);
        acc[nt] = mfma16(aw, bh, acc[nt]);
      }
    }
  }

  const int colh = (lane >> 5) * 4;
#pragma unroll
  for (int nt = 0; nt < 3; ++nt) {
    int n = wvx * 96 + nt * 32 + l31;
    int pos = (y0 + n / 48) * 48 + (n % 48);
    const int jblk = pos >> 5, jl = pos & 31;
    const int jc = pos >> 4, lhv = (pos >> 3) & 1, uv = pos & 7;
#pragma unroll
    for (int g = 0; g < 4; ++g) {
      int eb = e0 + g * 8 + colh;
      f32x4 sb = *(const f32x4*)(bias + eb);
      if (F == 0) {
        f16x4 hq;
#pragma unroll
        for (int j = 0; j < 4; ++j) hq[j] = (f16)(acc[nt][g * 4 + j] + sb[j]);
        *(f16x4*)(oq + ((size_t)b * NN + pos) * NE + eb) = hq;
      } else if (F == 1) {
        f16x4 hk;
#pragma unroll
        for (int j = 0; j < 4; ++j) hk[j] = (f16)(acc[nt][g * 4 + j] + sb[j]);
        *(f16x4*)(okf + ((((size_t)b * 72 + jblk) * 32 + (eb >> 4)) * 64 +
                         ((eb >> 3) & 1) * 32 + jl) * 8 + (eb & 7)) = hk;
      } else {
#pragma unroll
        for (int j = 0; j < 4; ++j) {
          int e = eb + j;
          ovf[((((size_t)b * 16 + (e >> 5)) * 144 + jc) * 64 + lhv * 32 + (e & 31)) * 8 + uv] =
              (f16)(acc[nt][g * 4 + j] + sb[j]);
        }
      }
    }
  }
}

// ---------------- flash attention v9 (S0/S1 chains, depth-8) ----------------
// Grid 576: b = bid&7 (XCD pin), i-tile = bid>>3 (32 rows). 18 jt of 128 j.
// acc = S0+S1(32) + O(64) = 96; arch ~68 -> ~164 <= 170 (3 waves/SIMD cap).
__global__ __launch_bounds__(256, 3) void attn(
    const f16* __restrict__ qt, const f16* __restrict__ kf,
    const f16* __restrict__ vf, float* __restrict__ out) {
  __shared__ __align__(16) f16 q_lds[16384];      // 32 frag blocks x 512 f16
  __shared__ __align__(16) f16 sP2[4096];         // 8 chunks x 64 lanes x 8 f16
  __shared__ __align__(16) float s_pmax[128];
  __shared__ __align__(16) float s_psum[128];

  const int tid = threadIdx.x;
  const int lane = tid & 63, wvx = tid >> 6;
  const int l31 = lane & 31, lh = lane >> 5;
  const int bid = blockIdx.x;
  const int b = bid & 7;
  const int i0 = (bid >> 3) * 32;

  // ---- stage q tile (32 x 512) once, into frag-block layout ----
  {
    const f16* qb = qt + ((size_t)b * NN + i0) * NE;
#pragma unroll
    for (int it = 0; it < 8; ++it) {
      int g = it * 256 + tid;
      int row = g >> 6, gr = g & 63;
      f16x8 v = *(const f16x8*)(qb + row * NE + gr * 8);
      *(f16x8*)(q_lds + (gr >> 1) * 512 + (gr & 1) * 256 + row * 8) = v;
    }
  }
  __syncthreads();

  float m_reg = -1e30f, l_reg = 0.f;
  f32x16 O[4];
#pragma unroll
  for (int nt = 0; nt < 4; ++nt)
#pragma unroll
    for (int i = 0; i < 16; ++i) O[nt][i] = 0.f;

  const f16* kfw = kf + (size_t)(b * 72 + wvx) * 16384 + lane * 8;
  const f16* vfw = vf + (size_t)(b * 16 + wvx * 4) * 73728 + lane * 8;
  const f16* qlw = q_lds + lane * 8;

  for (int jt = 0; jt < 18; ++jt) {
    // ---- Phase A: S = k.q^T, two interleaved acc chains, depth-8 k stream ----
    const f16* kfl = kfw + (size_t)jt * 4 * 16384;
    f32x16 S0, S1;
#pragma unroll
    for (int i = 0; i < 16; ++i) { S0[i] = 0.f; S1[i] = 0.f; }
    f16x8 kpipe[8];
#pragma unroll
    for (int t = 0; t < 8; ++t) kpipe[t] = *(const f16x8*)(kfl + t * 512);
#pragma unroll
    for (int c = 0; c < 32; ++c) {
      f16x8 ak = kpipe[c & 7];
      if (c + 8 < 32) kpipe[c & 7] = *(const f16x8*)(kfl + (c + 8) * 512);
      f16x8 aq = *(const f16x8*)(qlw + c * 512);
      if (c & 1) S1 = mfma16(ak, aq, S1);
      else       S0 = mfma16(ak, aq, S0);
    }
    f32x16 S;
#pragma unroll
    for (int r = 0; r < 16; ++r) S[r] = S0[r] + S1[r];
    // lane (i=l31, h=lh) holds S[i][j_local = (r&3)+8*(r>>2)+4*lh].

    // ---- Phase B: lane-local softmax, 2 barriers ----
    float wmax = S[0];
#pragma unroll
    for (int r = 1; r < 16; ++r) wmax = fmaxf(wmax, S[r]);
    wmax = fmaxf(wmax, __shfl_xor(wmax, 32, 64));
    if (lane < 32) s_pmax[l31 * 4 + wvx] = wmax;
    __syncthreads();                              // barrier 1 (also fences sP2)
    f32x4 pm4 = *(const f32x4*)(s_pmax + l31 * 4);
    float gmax = fmaxf(fmaxf(pm4[0], pm4[1]), fmaxf(pm4[2], pm4[3]));
    float mnew = fmaxf(m_reg, gmax);
    float alpha = 1.f;
    if (!__all(mnew == m_reg)) {                  // defer-max exact skip
      alpha = __expf(m_reg - mnew);
      m_reg = mnew;
#pragma unroll
      for (int nt = 0; nt < 4; ++nt)
#pragma unroll
        for (int r = 0; r < 16; ++r) O[nt][r] *= alpha;
    }

    f16 ph[16];
    float psum = 0.f;
#pragma unroll
    for (int r = 0; r < 16; ++r) {
      f16 p = (f16)__expf(S[r] - m_reg);
      ph[r] = p;
      psum += (float)p;
    }
    // pack quads -> B-frags via cross-half exchange, write sP2
    union Q4 { f16x4 h; int i2[2]; };
    Q4 q4[4];
#pragma unroll
    for (int t = 0; t < 4; ++t)
#pragma unroll
      for (int u = 0; u < 4; ++u) q4[t].h[u] = ph[t * 4 + u];
#pragma unroll
    for (int ks = 0; ks < 2; ++ks) {
      Q4 t1, t2;
      t1.i2[0] = __shfl_xor(q4[2 * ks + 1].i2[0], 32, 64);
      t1.i2[1] = __shfl_xor(q4[2 * ks + 1].i2[1], 32, 64);
      t2.i2[0] = __shfl_xor(q4[2 * ks].i2[0], 32, 64);
      t2.i2[1] = __shfl_xor(q4[2 * ks].i2[1], 32, 64);
      f16x4 first  = lh ? t1.h : q4[2 * ks].h;
      f16x4 second = lh ? q4[2 * ks + 1].h : t2.h;
      f16x8 frag;
#pragma unroll
      for (int u = 0; u < 4; ++u) { frag[u] = first[u]; frag[4 + u] = second[u]; }
      *(f16x8*)(sP2 + ((wvx * 2 + ks) * 64 + lane) * 8) = frag;
    }
    psum += __shfl_xor(psum, 32, 64);
    if (lane < 32) s_psum[l31 * 4 + wvx] = psum;
    __syncthreads();                              // barrier 2 (P + sums visible)
    f32x4 ps4 = *(const f32x4*)(s_psum + l31 * 4);
    l_reg = l_reg * alpha + (ps4[0] + ps4[1] + ps4[2] + ps4[3]);

    // ---- Phase C: O += V.P, depth-8 v stream — no barriers ----
    const f16* vfl = vfw + (size_t)jt * 8 * 512;
    f16x8 vpipe[8];
#pragma unroll
    for (int t = 0; t < 8; ++t) {
      int nt = t & 3, cg = t >> 2;
      vpipe[t] = *(const f16x8*)(vfl + (size_t)nt * 73728 + cg * 512);
    }
    f16x8 apc = *(const f16x8*)(sP2 + (0 * 64 + lane) * 8);
    f16x8 apn = *(const f16x8*)(sP2 + (1 * 64 + lane) * 8);
#pragma unroll
    for (int c = 0; c < 32; ++c) {
      int nt = c & 3, cg = c >> 2;
      f16x8 av = vpipe[c & 7];
      if (c + 8 < 32) {
        int c2 = c + 8, nt2 = c2 & 3, cg2 = c2 >> 2;
        vpipe[c & 7] = *(const f16x8*)(vfl + (size_t)nt2 * 73728 + cg2 * 512);
      }
      O[nt] = mfma16(av, apc, O[nt]);
      if (nt == 3) {
        apc = apn;
        if (cg + 2 < 8) apn = *(const f16x8*)(sP2 + ((cg + 2) * 64 + lane) * 8);
      }
    }
  }

  // ---- epilogue: per-lane normalize + v residual, direct coalesced stores ----
  float inv = 1.0f / l_reg;
  const int ii = i0 + l31;
  const int jcR = ii >> 4, lhR = (ii >> 3) & 1, uR = ii & 7;
#pragma unroll
  for (int nt = 0; nt < 4; ++nt) {
    const f16* vres = vf + ((((size_t)(b * 16 + wvx * 4 + nt)) * 144 + jcR) * 64 + lhR * 32) * 8 + uR;
    const int ebase = wvx * 128 + nt * 32;
#pragma unroll
    for (int r = 0; r < 16; ++r) {
      int el = (r & 3) + 8 * (r >> 2) + 4 * lh;
      float rv = (float)vres[el * 8];
      out[((size_t)b * NE + ebase + el) * NN + ii] = O[nt][r] * inv + rv;
    }
  }
}

// ---------------- launch ----------------
extern "C" void kernel_launch(void* const* d_in, const int* in_sizes, int n_in,
                              void* d_out, int out_size, void* d_ws, size_t ws_size,
                              hipStream_t stream) {
  const float* feat = (const float*)d_in[0];
  const float* Wq = (const float*)d_in[1];
  const float* bq = (const float*)d_in[2];
  const float* Wk = (const float*)d_in[3];
  const float* bk = (const float*)d_in[4];
  const float* Wv = (const float*)d_in[5];
  const float* bv = (const float*)d_in[6];
  float* out = (float*)d_out;

  char* ws = (char*)d_ws;
  size_t off = 0;
  auto alloc = [&](size_t bytes) {
    void* p = ws + off;
    off += (bytes + 255) & ~(size_t)255;
    return p;
  };
  const size_t FP = (size_t)NB * HP * HP * NC;     // 5,120,000
  const size_t WP = (size_t)9 * NE * NC;           // 1,179,648
  const size_t QP = (size_t)NB * NN * NE;          // 9,437,184
  f16* fp  = (f16*)alloc(FP * 2);
  f16* wq  = (f16*)alloc(WP * 2);
  f16* wk  = (f16*)alloc(WP * 2);
  f16* wv  = (f16*)alloc(WP * 2);
  f16* q_t = (f16*)alloc(QP * 2);
  f16* k_f = (f16*)alloc(QP * 2);
  f16* v_f = (f16*)alloc(QP * 2);

  pack_feat<<<dim3(NB, HP), dim3(256), 0, stream>>>(feat, fp);
  pack_w<<<dim3(NE * NC / 256), dim3(256), 0, stream>>>(Wq, Wk, Wv, wq, wk, wv);

  conv3_all<<<dim3(2304), dim3(256), 0, stream>>>(
      fp, wq, wk, wv, bq, bk, bv, q_t, k_f, v_f);

  attn<<<dim3(576), dim3(256), 0, stream>>>(q_t, k_f, v_f, out);
}